// Round 1
// baseline (552.201 us; speedup 1.0000x reference)
//
#include <hip/hip_runtime.h>
#include <hip/hip_cooperative_groups.h>
#include <math.h>

namespace cg = cooperative_groups;

#define N_NODES 20000
#define N_EDGES 320000
#define IN_CH   256
#define HID_CH  256
#define OUT_CH  128
#define CAP     64     // per-node slot capacity; P(deg>64)~1e-15 for 320k->20k uniform
#define GK      256
#define NBLK    512    // 2 blocks/CU on 256 CUs -- cooperative co-residency guaranteed
#define NTHR    256

typedef __attribute__((ext_vector_type(8))) short short8;
typedef __attribute__((ext_vector_type(8))) unsigned short ushort8;
typedef __attribute__((ext_vector_type(4))) unsigned short ushort4v;
typedef __attribute__((ext_vector_type(2))) unsigned short ushort2v;
typedef __attribute__((ext_vector_type(4))) float floatx4;
typedef __attribute__((ext_vector_type(2))) float floatx2;
typedef __attribute__((ext_vector_type(2))) _Float16 half2v;

// bf16 round-to-nearest-even helpers
static __device__ __forceinline__ unsigned short f2bf(float f) {
    unsigned int u = __float_as_uint(f);
    u += 0x7FFFu + ((u >> 16) & 1u);
    return (unsigned short)(u >> 16);
}
static __device__ __forceinline__ float bf2f(unsigned short h) {
    return __uint_as_float(((unsigned int)h) << 16);
}

struct Params {
    const float* doc; const int* row; const int* col;
    const float* W1; const float* b1; const float* W2; const float* b2;
    unsigned short* Ehi; unsigned short* Elo;          // doc_embeds split planes [N][256]
    unsigned short* W1thi; unsigned short* W1tlo;      // W1^T planes [256][256]
    unsigned short* W2thi; unsigned short* W2tlo;      // W2^T planes [128][256]
    int* deg; unsigned short* srcs;                    // slot-CSR
    _Float16* X1s;                                     // gemm out fp16 (layer2 reuses)
    unsigned short* H1hi; unsigned short* H1lo;        // relu(h1) split planes [N][256]
    float* out;
};

// ---------------------------------------------------------------------------
// GEMM tile: TM=64 x 128, BK=32, 4 waves (2x2), A pre-split bf16 hi/lo planes.
// 3-term compensation: hi*hi + hi*lo + lo*hi. Epilogue scales row by
// rsqrt(deg+1), stores fp16. Pure copy staging -- no f2bf in the K-loop.
// ---------------------------------------------------------------------------
static __device__ __forceinline__ void gemm_tile(
    const unsigned short* __restrict__ Ahi, const unsigned short* __restrict__ Alo,
    const unsigned short* __restrict__ Bhi, const unsigned short* __restrict__ Blo,
    const int* __restrict__ deg, _Float16* __restrict__ Cc,
    int M, int N, int m0, int n0,
    unsigned short (&As)[2][64][36], unsigned short (&Bs)[2][128][36])
{
    const int tid  = threadIdx.x;
    const int lane = tid & 63;
    const int wave = tid >> 6;
    const int wr = (wave >> 1) * 32;
    const int wc = (wave & 1) * 64;
    const int lm = lane & 15;
    const int lk = (lane >> 4) * 8;

    floatx4 acc[2][4];
#pragma unroll
    for (int i = 0; i < 2; ++i)
#pragma unroll
        for (int j = 0; j < 4; ++j) acc[i][j] = (floatx4){0.f, 0.f, 0.f, 0.f};

    const int ar  = tid >> 2;          // 0..63 : A row within tile
    const int ako = (tid & 3) * 8;     // k sub-chunk

    for (int k0 = 0; k0 < GK; k0 += 32) {
        {   // A staging: 64 rows x 32 k, hi+lo, 1 chunk/thread/plane
            ushort8 vh = {}, vl = {};
            if (m0 + ar < M) {
                size_t ga = (size_t)(m0 + ar) * GK + k0 + ako;
                vh = *(const ushort8*)(Ahi + ga);
                vl = *(const ushort8*)(Alo + ga);
            }
            *(ushort8*)&As[0][ar][ako] = vh;
            *(ushort8*)&As[1][ar][ako] = vl;
        }
#pragma unroll
        for (int c = 0; c < 2; ++c) {  // B staging: 128 rows x 32 k, hi+lo
            int ch = tid + c * NTHR;
            int r  = ch >> 2;
            int ko = (ch & 3) * 8;
            size_t gb = (size_t)(n0 + r) * GK + k0 + ko;
            *(ushort8*)&Bs[0][r][ko] = *(const ushort8*)(Bhi + gb);
            *(ushort8*)&Bs[1][r][ko] = *(const ushort8*)(Blo + gb);
        }
        __syncthreads();

        short8 ah[2], al[2], bh[4], bl[4];
#pragma unroll
        for (int i = 0; i < 2; ++i) {
            ah[i] = *(const short8*)&As[0][wr + i * 16 + lm][lk];
            al[i] = *(const short8*)&As[1][wr + i * 16 + lm][lk];
        }
#pragma unroll
        for (int j = 0; j < 4; ++j) {
            bh[j] = *(const short8*)&Bs[0][wc + j * 16 + lm][lk];
            bl[j] = *(const short8*)&Bs[1][wc + j * 16 + lm][lk];
        }
#pragma unroll
        for (int i = 0; i < 2; ++i)
#pragma unroll
            for (int j = 0; j < 4; ++j) {
                acc[i][j] = __builtin_amdgcn_mfma_f32_16x16x32_bf16(ah[i], bh[j], acc[i][j], 0, 0, 0);
                acc[i][j] = __builtin_amdgcn_mfma_f32_16x16x32_bf16(ah[i], bl[j], acc[i][j], 0, 0, 0);
                acc[i][j] = __builtin_amdgcn_mfma_f32_16x16x32_bf16(al[i], bh[j], acc[i][j], 0, 0, 0);
            }
        __syncthreads();
    }

#pragma unroll
    for (int i = 0; i < 2; ++i) {
#pragma unroll
        for (int r = 0; r < 4; ++r) {
            int rowi = m0 + wr + i * 16 + (lane >> 4) * 4 + r;
            if (rowi < M) {
                float dr = 1.0f / sqrtf((float)(deg[rowi] + 1));
#pragma unroll
                for (int j = 0; j < 4; ++j) {
                    Cc[(size_t)rowi * N + n0 + wc + j * 16 + lm] = (_Float16)(dr * acc[i][j][r]);
                }
            }
        }
    }
}

// ---------------------------------------------------------------------------
// XCD-sliced gather over ushort slot-CSR, fp16 X table. Slice = 32 ch;
// 16 lanes per node (half2/lane). With stride-NBLK virtual-block loops,
// vblk % NSLICE == blockIdx.x % NSLICE -> each persistent block (pinned CU,
// pinned XCD) always touches the SAME 1.28 MB X-slice: L2-resident.
// MODE 0: fp32 NT store to final out. MODE 1: relu + split bf16 hi/lo planes.
// ---------------------------------------------------------------------------
template <int CC, int NSLICE, int MODE>
static __device__ __forceinline__ void gather_tile(
    const _Float16* __restrict__ X, const int* __restrict__ deg,
    const unsigned short* __restrict__ srcs, const float* __restrict__ bias,
    float* __restrict__ outf, unsigned short* __restrict__ outhi,
    unsigned short* __restrict__ outlo, int n, int vblk)
{
    constexpr int SW = CC / NSLICE;
    static_assert(SW == 32, "slice must be 32 channels");
    const int slice = vblk % NSLICE;
    const int ngrp  = vblk / NSLICE;
    const int wave = threadIdx.x >> 6;
    const int lane = threadIdx.x & 63;
    const int gg = lane >> 4;          // node sub-group 0..3
    const int sl = lane & 15;          // sublane: 2 channels each
    const int node = ngrp * 16 + wave * 4 + gg;
    if (node >= n) return;             // returns from device fn only; no barrier inside
    const int choff = slice * SW + sl * 2;
    const size_t beg = (size_t)node * CAP;
    const int cnt = deg[node];

    float a0 = 0.f, a1 = 0.f;
    int e = 0;
    for (; e + 4 <= cnt; e += 4) {
        ushort4v s4 = *(const ushort4v*)(srcs + beg + e);
        half2v v0 = *(const half2v*)(X + (size_t)s4.x * CC + choff);
        half2v v1 = *(const half2v*)(X + (size_t)s4.y * CC + choff);
        half2v v2 = *(const half2v*)(X + (size_t)s4.z * CC + choff);
        half2v v3 = *(const half2v*)(X + (size_t)s4.w * CC + choff);
        a0 += (float)v0.x + (float)v1.x + (float)v2.x + (float)v3.x;
        a1 += (float)v0.y + (float)v1.y + (float)v2.y + (float)v3.y;
    }
    for (; e < cnt; ++e) {
        int r = srcs[beg + e];
        half2v v = *(const half2v*)(X + (size_t)r * CC + choff);
        a0 += (float)v.x; a1 += (float)v.y;
    }

    const float dc = 1.0f / sqrtf((float)(cnt + 1));
    half2v vsh = *(const half2v*)(X + (size_t)node * CC + choff);  // dinv-prescaled
    float2 bb = *(const float2*)(bias + choff);

    float o0 = dc * (a0 + (float)vsh.x) + bb.x;
    float o1 = dc * (a1 + (float)vsh.y) + bb.y;

    if constexpr (MODE == 1) {
        float r0 = fmaxf(o0, 0.f), r1 = fmaxf(o1, 0.f);
        ushort2v hv, lv;
        hv.x = f2bf(r0); lv.x = f2bf(r0 - bf2f(hv.x));
        hv.y = f2bf(r1); lv.y = f2bf(r1 - bf2f(hv.y));
        *(ushort2v*)(outhi + (size_t)node * CC + choff) = hv;
        *(ushort2v*)(outlo + (size_t)node * CC + choff) = lv;
    } else {
        floatx2 o = {o0, o1};
        __builtin_nontemporal_store(o, (floatx2*)(outf + (size_t)node * CC + choff));
    }
}

// ---------------------------------------------------------------------------
// One persistent cooperative kernel: prep | gemm1 | gather1 | gemm2 | gather2
// separated by grid.sync(). 512 blocks x 256 thr, 2 blocks/CU co-resident
// (LDS 27.6 KB, launch_bounds(256,2)).
// ---------------------------------------------------------------------------
__global__ __launch_bounds__(NTHR, 2)
void fused_gcn(Params p)
{
    __shared__ unsigned short As[2][64][36];
    __shared__ unsigned short Bs[2][128][36];
    cg::grid_group gridg = cg::this_grid();
    const int tid = threadIdx.x;
    const int bid = blockIdx.x;
    const int g   = bid * NTHR + tid;
    const int gsz = NBLK * NTHR;

    // ---- Phase A: weight transpose/split + doc_embeds split + slot-CSR ----
    for (int t = g; t < (IN_CH * HID_CH) / 16; t += gsz) {
        int n = t >> 4;
        int kc = (t & 15) * 16;
        ushort8 h0, l0, h1, l1;
#pragma unroll
        for (int j = 0; j < 8; ++j) {
            float x = p.W1[(size_t)(kc + j) * HID_CH + n];
            h0[j] = f2bf(x); l0[j] = f2bf(x - bf2f(h0[j]));
            float y = p.W1[(size_t)(kc + 8 + j) * HID_CH + n];
            h1[j] = f2bf(y); l1[j] = f2bf(y - bf2f(h1[j]));
        }
        *(ushort8*)(p.W1thi + (size_t)n * IN_CH + kc)     = h0;
        *(ushort8*)(p.W1thi + (size_t)n * IN_CH + kc + 8) = h1;
        *(ushort8*)(p.W1tlo + (size_t)n * IN_CH + kc)     = l0;
        *(ushort8*)(p.W1tlo + (size_t)n * IN_CH + kc + 8) = l1;
    }
    for (int t = g; t < (HID_CH * OUT_CH) / 16; t += gsz) {
        int n = t >> 4;
        int kc = (t & 15) * 16;
        ushort8 h0, l0, h1, l1;
#pragma unroll
        for (int j = 0; j < 8; ++j) {
            float x = p.W2[(size_t)(kc + j) * OUT_CH + n];
            h0[j] = f2bf(x); l0[j] = f2bf(x - bf2f(h0[j]));
            float y = p.W2[(size_t)(kc + 8 + j) * OUT_CH + n];
            h1[j] = f2bf(y); l1[j] = f2bf(y - bf2f(h1[j]));
        }
        *(ushort8*)(p.W2thi + (size_t)n * HID_CH + kc)     = h0;
        *(ushort8*)(p.W2thi + (size_t)n * HID_CH + kc + 8) = h1;
        *(ushort8*)(p.W2tlo + (size_t)n * HID_CH + kc)     = l0;
        *(ushort8*)(p.W2tlo + (size_t)n * HID_CH + kc + 8) = l1;
    }
    for (int t = g; t < (N_NODES * IN_CH) / 16; t += gsz) {
        int node = t >> 4;
        int kc = (t & 15) * 16;
        const float* ap = p.doc + (size_t)node * IN_CH + kc;
        float4 f0 = *(const float4*)(ap);
        float4 f1 = *(const float4*)(ap + 4);
        float4 f2 = *(const float4*)(ap + 8);
        float4 f3 = *(const float4*)(ap + 12);
        float xs[16] = {f0.x, f0.y, f0.z, f0.w, f1.x, f1.y, f1.z, f1.w,
                        f2.x, f2.y, f2.z, f2.w, f3.x, f3.y, f3.z, f3.w};
        ushort8 h0, l0, h1, l1;
#pragma unroll
        for (int j = 0; j < 8; ++j) {
            h0[j] = f2bf(xs[j]);     l0[j] = f2bf(xs[j] - bf2f(h0[j]));
            h1[j] = f2bf(xs[8 + j]); l1[j] = f2bf(xs[8 + j] - bf2f(h1[j]));
        }
        *(ushort8*)(p.Ehi + (size_t)node * IN_CH + kc)     = h0;
        *(ushort8*)(p.Ehi + (size_t)node * IN_CH + kc + 8) = h1;
        *(ushort8*)(p.Elo + (size_t)node * IN_CH + kc)     = l0;
        *(ushort8*)(p.Elo + (size_t)node * IN_CH + kc + 8) = l1;
    }
    for (int i = g; i < N_EDGES; i += gsz) {   // slot-CSR (deg pre-zeroed by memset)
        int c = p.col[i];
        int r = p.row[i];
        int q = atomicAdd(&p.deg[c], 1);
        p.srcs[(size_t)c * CAP + q] = (unsigned short)r;
    }
    gridg.sync();

    // ---- Phase B: gemm1 -> X1s fp16 (rows dinv-prescaled) ----
    for (int tile = bid; tile < 2 * ((N_NODES + 63) / 64); tile += NBLK)
        gemm_tile(p.Ehi, p.Elo, p.W1thi, p.W1tlo, p.deg, p.X1s,
                  N_NODES, HID_CH, (tile >> 1) * 64, (tile & 1) * 128, As, Bs);
    gridg.sync();

    // ---- Phase C: gather1 + relu -> H1 hi/lo planes ----
    for (int v = bid; v < ((N_NODES + 15) / 16) * 8; v += NBLK)
        gather_tile<HID_CH, 8, 1>(p.X1s, p.deg, p.srcs, p.b1,
                                  nullptr, p.H1hi, p.H1lo, N_NODES, v);
    gridg.sync();

    // ---- Phase D: gemm2 -> X2s (aliases X1s) ----
    for (int tile = bid; tile < (N_NODES + 63) / 64; tile += NBLK)
        gemm_tile(p.H1hi, p.H1lo, p.W2thi, p.W2tlo, p.deg, p.X1s,
                  N_NODES, OUT_CH, tile * 64, 0, As, Bs);
    gridg.sync();

    // ---- Phase E: gather2 -> out fp32 ----
    for (int v = bid; v < ((N_NODES + 15) / 16) * 4; v += NBLK)
        gather_tile<OUT_CH, 4, 0>(p.X1s, p.deg, p.srcs, p.b2,
                                  p.out, nullptr, nullptr, N_NODES, v);
}

// ---------------------------------------------------------------------------
extern "C" void kernel_launch(void* const* d_in, const int* in_sizes, int n_in,
                              void* d_out, int out_size, void* d_ws, size_t ws_size,
                              hipStream_t stream)
{
    Params p;
    p.doc = (const float*)d_in[0];                 // [20000,256]
    const int* ei = (const int*)d_in[1];           // [2,320000] (int32 on device)
    p.row = ei;
    p.col = ei + N_EDGES;
    p.W1 = (const float*)d_in[2];
    p.b1 = (const float*)d_in[3];
    p.W2 = (const float*)d_in[4];
    p.b2 = (const float*)d_in[5];
    p.out = (float*)d_out;

    char* ws = (char*)d_ws;
    auto au = [](size_t x) { return (x + 255) / 256 * 256; };
    p.X1s   = (_Float16*)ws;       ws += au((size_t)N_NODES * HID_CH * 2);  // 10.24 MB
    p.Ehi   = (unsigned short*)ws; ws += au((size_t)N_NODES * IN_CH * 2);
    p.Elo   = (unsigned short*)ws; ws += au((size_t)N_NODES * IN_CH * 2);
    p.H1hi  = (unsigned short*)ws; ws += au((size_t)N_NODES * HID_CH * 2);
    p.H1lo  = (unsigned short*)ws; ws += au((size_t)N_NODES * HID_CH * 2);
    p.W1thi = (unsigned short*)ws; ws += au((size_t)IN_CH * HID_CH * 2);
    p.W1tlo = (unsigned short*)ws; ws += au((size_t)IN_CH * HID_CH * 2);
    p.W2thi = (unsigned short*)ws; ws += au((size_t)HID_CH * OUT_CH * 2);
    p.W2tlo = (unsigned short*)ws; ws += au((size_t)HID_CH * OUT_CH * 2);
    p.deg   = (int*)ws;            ws += au((size_t)N_NODES * 4);
    p.srcs  = (unsigned short*)ws;                                           // 2.56 MB

    hipMemsetAsync(p.deg, 0, (size_t)N_NODES * 4, stream);
    void* args[] = { &p };
    hipLaunchCooperativeKernel((const void*)fused_gcn, dim3(NBLK), dim3(NTHR),
                               args, 0, stream);
}

// Round 2
// 181.862 us; speedup vs baseline: 3.0364x; 3.0364x over previous
//
#include <hip/hip_runtime.h>
#include <math.h>

#define N_NODES 20000
#define N_EDGES 320000
#define IN_CH   256
#define HID_CH  256
#define OUT_CH  128
#define CAP     64     // per-node slot capacity; P(deg>64)~1e-15 for 320k->20k uniform
#define GK      256

typedef __attribute__((ext_vector_type(8))) short short8;
typedef __attribute__((ext_vector_type(8))) unsigned short ushort8;
typedef __attribute__((ext_vector_type(4))) unsigned short ushort4v;
typedef __attribute__((ext_vector_type(2))) unsigned short ushort2v;
typedef __attribute__((ext_vector_type(4))) float floatx4;
typedef __attribute__((ext_vector_type(2))) float floatx2;
typedef __attribute__((ext_vector_type(2))) _Float16 half2v;

// bf16 round-to-nearest-even helpers
static __device__ __forceinline__ unsigned short f2bf(float f) {
    unsigned int u = __float_as_uint(f);
    u += 0x7FFFu + ((u >> 16) & 1u);
    return (unsigned short)(u >> 16);
}
static __device__ __forceinline__ float bf2f(unsigned short h) {
    return __uint_as_float(((unsigned int)h) << 16);
}

// ---------------------------------------------------------------------------
// fused prep: weight transpose/split + doc_embeds hi/lo split + slot-CSR fill.
// deg must be zeroed beforehand (hipMemsetAsync). All parts are independent
// grid-stride loops; edge atomics are latency-bound so the streaming split
// traffic overlaps underneath them.
// ---------------------------------------------------------------------------
__global__ __launch_bounds__(256)
void prep_kernel(const float* __restrict__ W1, const float* __restrict__ W2,
                 const float* __restrict__ doc,
                 unsigned short* __restrict__ W1thi, unsigned short* __restrict__ W1tlo,
                 unsigned short* __restrict__ W2thi, unsigned short* __restrict__ W2tlo,
                 unsigned short* __restrict__ Ehi, unsigned short* __restrict__ Elo,
                 const int* __restrict__ row, const int* __restrict__ col,
                 int* __restrict__ deg, unsigned short* __restrict__ srcs) {
    const int g = blockIdx.x * blockDim.x + threadIdx.x;
    const int gsz = gridDim.x * blockDim.x;
    // W1^T planes (line-contiguous in K)
    for (int t = g; t < (IN_CH * HID_CH) / 16; t += gsz) {
        int n = t >> 4;
        int kc = (t & 15) * 16;
        ushort8 h0, l0, h1, l1;
#pragma unroll
        for (int j = 0; j < 8; ++j) {
            float x = W1[(size_t)(kc + j) * HID_CH + n];
            h0[j] = f2bf(x); l0[j] = f2bf(x - bf2f(h0[j]));
            float y = W1[(size_t)(kc + 8 + j) * HID_CH + n];
            h1[j] = f2bf(y); l1[j] = f2bf(y - bf2f(h1[j]));
        }
        *(ushort8*)(W1thi + (size_t)n * IN_CH + kc)     = h0;
        *(ushort8*)(W1thi + (size_t)n * IN_CH + kc + 8) = h1;
        *(ushort8*)(W1tlo + (size_t)n * IN_CH + kc)     = l0;
        *(ushort8*)(W1tlo + (size_t)n * IN_CH + kc + 8) = l1;
    }
    // W2^T planes
    for (int t = g; t < (HID_CH * OUT_CH) / 16; t += gsz) {
        int n = t >> 4;
        int kc = (t & 15) * 16;
        ushort8 h0, l0, h1, l1;
#pragma unroll
        for (int j = 0; j < 8; ++j) {
            float x = W2[(size_t)(kc + j) * OUT_CH + n];
            h0[j] = f2bf(x); l0[j] = f2bf(x - bf2f(h0[j]));
            float y = W2[(size_t)(kc + 8 + j) * OUT_CH + n];
            h1[j] = f2bf(y); l1[j] = f2bf(y - bf2f(h1[j]));
        }
        *(ushort8*)(W2thi + (size_t)n * HID_CH + kc)     = h0;
        *(ushort8*)(W2thi + (size_t)n * HID_CH + kc + 8) = h1;
        *(ushort8*)(W2tlo + (size_t)n * HID_CH + kc)     = l0;
        *(ushort8*)(W2tlo + (size_t)n * HID_CH + kc + 8) = l1;
    }
    // doc_embeds -> bf16 hi/lo planes (row-major, K-contiguous)
    for (int t = g; t < (N_NODES * IN_CH) / 16; t += gsz) {
        int node = t >> 4;
        int kc = (t & 15) * 16;
        const float* ap = doc + (size_t)node * IN_CH + kc;
        float4 f0 = *(const float4*)(ap);
        float4 f1 = *(const float4*)(ap + 4);
        float4 f2 = *(const float4*)(ap + 8);
        float4 f3 = *(const float4*)(ap + 12);
        float xs[16] = {f0.x, f0.y, f0.z, f0.w, f1.x, f1.y, f1.z, f1.w,
                        f2.x, f2.y, f2.z, f2.w, f3.x, f3.y, f3.z, f3.w};
        ushort8 h0, l0, h1, l1;
#pragma unroll
        for (int j = 0; j < 8; ++j) {
            h0[j] = f2bf(xs[j]);     l0[j] = f2bf(xs[j] - bf2f(h0[j]));
            h1[j] = f2bf(xs[8 + j]); l1[j] = f2bf(xs[8 + j] - bf2f(h1[j]));
        }
        *(ushort8*)(Ehi + (size_t)node * IN_CH + kc)     = h0;
        *(ushort8*)(Ehi + (size_t)node * IN_CH + kc + 8) = h1;
        *(ushort8*)(Elo + (size_t)node * IN_CH + kc)     = l0;
        *(ushort8*)(Elo + (size_t)node * IN_CH + kc + 8) = l1;
    }
    // slot-CSR build: deg count + bucket fill (no scan)
    for (int i = g; i < N_EDGES; i += gsz) {
        int c = col[i];
        int r = row[i];
        int p = atomicAdd(&deg[c], 1);
        srcs[(size_t)c * CAP + p] = (unsigned short)r;
    }
}

// ---------------------------------------------------------------------------
// split-bf16 MFMA GEMM, A AND B both pre-split hi/lo planes -> staging is a
// pure 16B copy (zero conversion VALU in the K-loop).
// 64 x TN tile, BK=32, 4 waves (2x2), 3-term compensation hi*hi+hi*lo+lo*hi.
// Epilogue scales row by rsqrt(deg+1), stores fp16.
// ---------------------------------------------------------------------------
template <int TN>
__global__ __launch_bounds__(256)
void gemm_mfma_kernel(const unsigned short* __restrict__ Ahi, const unsigned short* __restrict__ Alo,
                      const unsigned short* __restrict__ Bthi, const unsigned short* __restrict__ Btlo,
                      const int* __restrict__ deg, _Float16* __restrict__ C, int M, int N) {
    constexpr int NJ = TN / 32;          // 16-col MFMA tiles per wave
    __shared__ unsigned short As[2][64][36];
    __shared__ unsigned short Bs[2][TN][36];
    const int tid = threadIdx.x;
    const int m0 = blockIdx.y * 64;
    const int n0 = blockIdx.x * TN;
    const int lane = tid & 63;
    const int wave = tid >> 6;
    const int wr = (wave >> 1) * 32;
    const int wc = (wave & 1) * (TN / 2);
    const int lm = lane & 15;
    const int lk = (lane >> 4) * 8;

    floatx4 acc[2][NJ];
#pragma unroll
    for (int i = 0; i < 2; ++i)
#pragma unroll
        for (int j = 0; j < NJ; ++j) acc[i][j] = (floatx4){0.f, 0.f, 0.f, 0.f};

    const int ar  = tid >> 2;          // 0..63 : A row within tile
    const int ako = (tid & 3) * 8;     // k sub-chunk

    for (int k0 = 0; k0 < GK; k0 += 32) {
        {   // A staging: 64 rows x 32 k, hi+lo, pure copy
            ushort8 vh = {}, vl = {};
            if (m0 + ar < M) {
                size_t ga = (size_t)(m0 + ar) * GK + k0 + ako;
                vh = *(const ushort8*)(Ahi + ga);
                vl = *(const ushort8*)(Alo + ga);
            }
            *(ushort8*)&As[0][ar][ako] = vh;
            *(ushort8*)&As[1][ar][ako] = vl;
        }
#pragma unroll
        for (int c = 0; c < TN / 64; ++c) {  // B staging: TN rows x 32 k, pure copy
            int ch = tid + c * 256;
            int r  = ch >> 2;
            int ko = (ch & 3) * 8;
            size_t gb = (size_t)(n0 + r) * GK + k0 + ko;
            *(ushort8*)&Bs[0][r][ko] = *(const ushort8*)(Bthi + gb);
            *(ushort8*)&Bs[1][r][ko] = *(const ushort8*)(Btlo + gb);
        }
        __syncthreads();

        short8 ah[2], al[2], bh[NJ], bl[NJ];
#pragma unroll
        for (int i = 0; i < 2; ++i) {
            ah[i] = *(const short8*)&As[0][wr + i * 16 + lm][lk];
            al[i] = *(const short8*)&As[1][wr + i * 16 + lm][lk];
        }
#pragma unroll
        for (int j = 0; j < NJ; ++j) {
            bh[j] = *(const short8*)&Bs[0][wc + j * 16 + lm][lk];
            bl[j] = *(const short8*)&Bs[1][wc + j * 16 + lm][lk];
        }
#pragma unroll
        for (int i = 0; i < 2; ++i)
#pragma unroll
            for (int j = 0; j < NJ; ++j) {
                acc[i][j] = __builtin_amdgcn_mfma_f32_16x16x32_bf16(ah[i], bh[j], acc[i][j], 0, 0, 0);
                acc[i][j] = __builtin_amdgcn_mfma_f32_16x16x32_bf16(ah[i], bl[j], acc[i][j], 0, 0, 0);
                acc[i][j] = __builtin_amdgcn_mfma_f32_16x16x32_bf16(al[i], bh[j], acc[i][j], 0, 0, 0);
            }
        __syncthreads();
    }

#pragma unroll
    for (int i = 0; i < 2; ++i) {
#pragma unroll
        for (int r = 0; r < 4; ++r) {
            int rowi = m0 + wr + i * 16 + (lane >> 4) * 4 + r;
            if (rowi < M) {
                float dr = 1.0f / sqrtf((float)(deg[rowi] + 1));
#pragma unroll
                for (int j = 0; j < NJ; ++j) {
                    C[(size_t)rowi * N + n0 + wc + j * 16 + lm] = (_Float16)(dr * acc[i][j][r]);
                }
            }
        }
    }
}

// ---------------------------------------------------------------------------
// XCD-sliced gather over ushort slot-CSR, fp16 X table. Slice = 32 ch;
// 16 lanes per node (half2/lane) -> 4 node-groups/wave. One edge row-slice =
// 64 B contiguous. X rows dinv[src]-prescaled by GEMM epilogue.
// MODE 0: fp32 NT store to final out. MODE 1: relu + bf16 hi/lo planes
// (feeds gemm2's pure-copy staging; also more accurate than fp16).
// ---------------------------------------------------------------------------
template <int C, int NSLICE, int MODE>
__global__ __launch_bounds__(256)
void gather_sliced_kernel(const _Float16* __restrict__ X, const int* __restrict__ deg,
                          const unsigned short* __restrict__ srcs,
                          const float* __restrict__ bias, float* __restrict__ outf,
                          unsigned short* __restrict__ outhi, unsigned short* __restrict__ outlo,
                          int n) {
    constexpr int SW = C / NSLICE;
    static_assert(SW == 32, "slice must be 32 channels");
    const int slice = blockIdx.x % NSLICE;
    const int ngrp  = blockIdx.x / NSLICE;
    const int wave = threadIdx.x >> 6;
    const int lane = threadIdx.x & 63;
    const int g  = lane >> 4;          // node sub-group 0..3
    const int sl = lane & 15;          // sublane: 2 channels each
    const int node = ngrp * 16 + wave * 4 + g;
    if (node >= n) return;
    const int choff = slice * SW + sl * 2;
    const size_t beg = (size_t)node * CAP;
    const int cnt = deg[node];

    float a0 = 0.f, a1 = 0.f;
    int e = 0;
    for (; e + 4 <= cnt; e += 4) {
        ushort4v s4 = *(const ushort4v*)(srcs + beg + e);
        half2v v0 = *(const half2v*)(X + (size_t)s4.x * C + choff);
        half2v v1 = *(const half2v*)(X + (size_t)s4.y * C + choff);
        half2v v2 = *(const half2v*)(X + (size_t)s4.z * C + choff);
        half2v v3 = *(const half2v*)(X + (size_t)s4.w * C + choff);
        a0 += (float)v0.x + (float)v1.x + (float)v2.x + (float)v3.x;
        a1 += (float)v0.y + (float)v1.y + (float)v2.y + (float)v3.y;
    }
    for (; e < cnt; ++e) {
        int r = srcs[beg + e];
        half2v v = *(const half2v*)(X + (size_t)r * C + choff);
        a0 += (float)v.x; a1 += (float)v.y;
    }

    const float dc = 1.0f / sqrtf((float)(cnt + 1));
    half2v vsh = *(const half2v*)(X + (size_t)node * C + choff);  // dinv-prescaled
    float2 bb = *(const float2*)(bias + choff);

    float o0 = dc * (a0 + (float)vsh.x) + bb.x;
    float o1 = dc * (a1 + (float)vsh.y) + bb.y;

    if constexpr (MODE == 1) {
        float r0 = fmaxf(o0, 0.f), r1 = fmaxf(o1, 0.f);
        ushort2v hv, lv;
        hv.x = f2bf(r0); lv.x = f2bf(r0 - bf2f(hv.x));
        hv.y = f2bf(r1); lv.y = f2bf(r1 - bf2f(hv.y));
        *(ushort2v*)(outhi + (size_t)node * C + choff) = hv;
        *(ushort2v*)(outlo + (size_t)node * C + choff) = lv;
    } else {
        floatx2 o = {o0, o1};
        __builtin_nontemporal_store(o, (floatx2*)(outf + (size_t)node * C + choff));
    }
}

// ---------------------------------------------------------------------------
extern "C" void kernel_launch(void* const* d_in, const int* in_sizes, int n_in,
                              void* d_out, int out_size, void* d_ws, size_t ws_size,
                              hipStream_t stream) {
    const float* doc_embeds = (const float*)d_in[0];   // [20000,256]
    const int*   edge_index = (const int*)d_in[1];     // [2,320000]
    const float* W1 = (const float*)d_in[2];           // [256,256]
    const float* b1 = (const float*)d_in[3];           // [256]
    const float* W2 = (const float*)d_in[4];           // [256,128]
    const float* b2 = (const float*)d_in[5];           // [128]
    float* out = (float*)d_out;                        // [20000,128]

    const int* row = edge_index;            // sources
    const int* col = edge_index + N_EDGES;  // destinations

    // ---------------- workspace layout (256B aligned) ----------------
    char* ws = (char*)d_ws;
    auto au = [](size_t x) { return (x + 255) / 256 * 256; };

    _Float16* X1s = (_Float16*)ws;      ws += au((size_t)N_NODES * HID_CH * 2);  // 10.24 MB (gemm2 out aliases)
    unsigned short* Ehi  = (unsigned short*)ws; ws += au((size_t)N_NODES * IN_CH * 2);
    unsigned short* Elo  = (unsigned short*)ws; ws += au((size_t)N_NODES * IN_CH * 2);
    unsigned short* H1hi = (unsigned short*)ws; ws += au((size_t)N_NODES * HID_CH * 2);
    unsigned short* H1lo = (unsigned short*)ws; ws += au((size_t)N_NODES * HID_CH * 2);
    unsigned short* W1thi = (unsigned short*)ws; ws += au((size_t)IN_CH * HID_CH * 2);
    unsigned short* W1tlo = (unsigned short*)ws; ws += au((size_t)IN_CH * HID_CH * 2);
    unsigned short* W2thi = (unsigned short*)ws; ws += au((size_t)HID_CH * OUT_CH * 2);
    unsigned short* W2tlo = (unsigned short*)ws; ws += au((size_t)HID_CH * OUT_CH * 2);
    int*            deg   = (int*)ws;            ws += au((size_t)N_NODES * 4);
    unsigned short* srcs  = (unsigned short*)ws; // 20000*64*2 = 2.56 MB

    // ---------------- prep ----------------
    hipMemsetAsync(deg, 0, (size_t)N_NODES * 4, stream);
    prep_kernel<<<(N_EDGES + 255) / 256, 256, 0, stream>>>(
        W1, W2, doc_embeds, W1thi, W1tlo, W2thi, W2tlo, Ehi, Elo, row, col, deg, srcs);

    // ---------------- layer 1 ----------------
    {
        dim3 grid(HID_CH / 128, (N_NODES + 63) / 64);   // (2, 313) = 626 blocks
        gemm_mfma_kernel<128><<<grid, 256, 0, stream>>>(
            Ehi, Elo, W1thi, W1tlo, deg, X1s, N_NODES, HID_CH);
    }
    gather_sliced_kernel<HID_CH, 8, 1><<<((N_NODES + 15) / 16) * 8, 256, 0, stream>>>(
        X1s, deg, srcs, b1, nullptr, H1hi, H1lo, N_NODES);

    // ---------------- layer 2 ----------------
    {
        dim3 grid(OUT_CH / 64, (N_NODES + 63) / 64);    // (2, 313) = 626 blocks
        gemm_mfma_kernel<64><<<grid, 256, 0, stream>>>(
            H1hi, H1lo, W2thi, W2tlo, deg, X1s, N_NODES, OUT_CH);
    }
    gather_sliced_kernel<OUT_CH, 4, 0><<<((N_NODES + 15) / 16) * 4, 256, 0, stream>>>(
        X1s, deg, srcs, b2, out, nullptr, nullptr, N_NODES);
}

// Round 3
// 176.332 us; speedup vs baseline: 3.1316x; 1.0314x over previous
//
#include <hip/hip_runtime.h>
#include <math.h>

#define N_NODES 20000
#define N_EDGES 320000
#define IN_CH   256
#define HID_CH  256
#define OUT_CH  128
#define CAP     64     // per-node slot capacity; P(deg>64)~1e-15 for 320k->20k uniform
#define GK      256

typedef __attribute__((ext_vector_type(8))) short short8;
typedef __attribute__((ext_vector_type(8))) unsigned short ushort8;
typedef __attribute__((ext_vector_type(4))) unsigned short ushort4v;
typedef __attribute__((ext_vector_type(2))) unsigned short ushort2v;
typedef __attribute__((ext_vector_type(4))) float floatx4;
typedef __attribute__((ext_vector_type(2))) float floatx2;
typedef __attribute__((ext_vector_type(2))) _Float16 half2v;

// bf16 round-to-nearest-even helpers
static __device__ __forceinline__ unsigned short f2bf(float f) {
    unsigned int u = __float_as_uint(f);
    u += 0x7FFFu + ((u >> 16) & 1u);
    return (unsigned short)(u >> 16);
}
static __device__ __forceinline__ float bf2f(unsigned short h) {
    return __uint_as_float(((unsigned int)h) << 16);
}

// ---------------------------------------------------------------------------
// prep: weight transpose/split (line-contiguous) + slot-CSR fill.
// deg must be zeroed beforehand (hipMemsetAsync). Doc embeds are NOT
// pre-split (round-2 A/B showed the extra 41 MB of traffic costs more than
// the in-GEMM split VALU it saves).
// ---------------------------------------------------------------------------
__global__ __launch_bounds__(256)
void prep_kernel(const float* __restrict__ W1, const float* __restrict__ W2,
                 unsigned short* __restrict__ W1thi, unsigned short* __restrict__ W1tlo,
                 unsigned short* __restrict__ W2thi, unsigned short* __restrict__ W2tlo,
                 const int* __restrict__ row, const int* __restrict__ col,
                 int* __restrict__ deg, unsigned short* __restrict__ srcs) {
    const int g = blockIdx.x * blockDim.x + threadIdx.x;
    const int gsz = gridDim.x * blockDim.x;
    // W1^T planes (K-contiguous lines)
    for (int t = g; t < (IN_CH * HID_CH) / 16; t += gsz) {
        int n = t >> 4;
        int kc = (t & 15) * 16;
        ushort8 h0, l0, h1, l1;
#pragma unroll
        for (int j = 0; j < 8; ++j) {
            float x = W1[(size_t)(kc + j) * HID_CH + n];
            h0[j] = f2bf(x); l0[j] = f2bf(x - bf2f(h0[j]));
            float y = W1[(size_t)(kc + 8 + j) * HID_CH + n];
            h1[j] = f2bf(y); l1[j] = f2bf(y - bf2f(h1[j]));
        }
        *(ushort8*)(W1thi + (size_t)n * IN_CH + kc)     = h0;
        *(ushort8*)(W1thi + (size_t)n * IN_CH + kc + 8) = h1;
        *(ushort8*)(W1tlo + (size_t)n * IN_CH + kc)     = l0;
        *(ushort8*)(W1tlo + (size_t)n * IN_CH + kc + 8) = l1;
    }
    // W2^T planes
    for (int t = g; t < (HID_CH * OUT_CH) / 16; t += gsz) {
        int n = t >> 4;
        int kc = (t & 15) * 16;
        ushort8 h0, l0, h1, l1;
#pragma unroll
        for (int j = 0; j < 8; ++j) {
            float x = W2[(size_t)(kc + j) * OUT_CH + n];
            h0[j] = f2bf(x); l0[j] = f2bf(x - bf2f(h0[j]));
            float y = W2[(size_t)(kc + 8 + j) * OUT_CH + n];
            h1[j] = f2bf(y); l1[j] = f2bf(y - bf2f(h1[j]));
        }
        *(ushort8*)(W2thi + (size_t)n * HID_CH + kc)     = h0;
        *(ushort8*)(W2thi + (size_t)n * HID_CH + kc + 8) = h1;
        *(ushort8*)(W2tlo + (size_t)n * HID_CH + kc)     = l0;
        *(ushort8*)(W2tlo + (size_t)n * HID_CH + kc + 8) = l1;
    }
    // slot-CSR build: deg count + bucket fill (no scan)
    for (int i = g; i < N_EDGES; i += gsz) {
        int c = col[i];
        int r = row[i];
        int p = atomicAdd(&deg[c], 1);
        srcs[(size_t)c * CAP + p] = (unsigned short)r;
    }
}

// ---------------------------------------------------------------------------
// split-bf16 MFMA GEMM. 64 x TN tile covering the FULL N in one block
// (grid.x == 1) so A is read exactly once. BK=32, 4 waves (2x2),
// 3-term compensation hi*hi + hi*lo + lo*hi.
// AMODE 1: A fp32, split in-register during staging (doc_embeds path).
// AMODE 3: A pre-split bf16 hi/lo planes, pure-copy staging (H1 path).
// Epilogue scales row by rsqrt(deg+1), stores fp16.
// ---------------------------------------------------------------------------
template <int AMODE, int TN>
__global__ __launch_bounds__(256, 2)
void gemm_mfma_kernel(const float* __restrict__ Afp,
                      const unsigned short* __restrict__ Ahi, const unsigned short* __restrict__ Alo,
                      const unsigned short* __restrict__ Bthi, const unsigned short* __restrict__ Btlo,
                      const int* __restrict__ deg, _Float16* __restrict__ C, int M, int N) {
    constexpr int NJ = TN / 32;          // 16-col MFMA tiles per wave
    __shared__ unsigned short As[2][64][36];
    __shared__ unsigned short Bs[2][TN][36];
    const int tid = threadIdx.x;
    const int m0 = blockIdx.y * 64;
    const int lane = tid & 63;
    const int wave = tid >> 6;
    const int wr = (wave >> 1) * 32;
    const int wc = (wave & 1) * (TN / 2);
    const int lm = lane & 15;
    const int lk = (lane >> 4) * 8;

    floatx4 acc[2][NJ];
#pragma unroll
    for (int i = 0; i < 2; ++i)
#pragma unroll
        for (int j = 0; j < NJ; ++j) acc[i][j] = (floatx4){0.f, 0.f, 0.f, 0.f};

    const int ar  = tid >> 2;          // 0..63 : A row within tile
    const int ako = (tid & 3) * 8;     // k sub-chunk

    for (int k0 = 0; k0 < GK; k0 += 32) {
        {   // A staging: 64 rows x 32 k, hi+lo
            ushort8 vh = {}, vl = {};
            if (m0 + ar < M) {
                if (AMODE == 1) {
                    const float* ap = Afp + (size_t)(m0 + ar) * GK + k0 + ako;
                    float4 f0 = *(const float4*)ap;
                    float4 f1 = *(const float4*)(ap + 4);
                    float xs[8] = {f0.x, f0.y, f0.z, f0.w, f1.x, f1.y, f1.z, f1.w};
#pragma unroll
                    for (int j = 0; j < 8; ++j) {
                        vh[j] = f2bf(xs[j]);
                        vl[j] = f2bf(xs[j] - bf2f(vh[j]));
                    }
                } else {
                    size_t ga = (size_t)(m0 + ar) * GK + k0 + ako;
                    vh = *(const ushort8*)(Ahi + ga);
                    vl = *(const ushort8*)(Alo + ga);
                }
            }
            *(ushort8*)&As[0][ar][ako] = vh;
            *(ushort8*)&As[1][ar][ako] = vl;
        }
#pragma unroll
        for (int c = 0; c < TN / 64; ++c) {  // B staging: TN rows x 32 k, pure copy
            int ch = tid + c * 256;
            int r  = ch >> 2;
            int ko = (ch & 3) * 8;
            size_t gb = (size_t)r * GK + k0 + ko;
            *(ushort8*)&Bs[0][r][ko] = *(const ushort8*)(Bthi + gb);
            *(ushort8*)&Bs[1][r][ko] = *(const ushort8*)(Btlo + gb);
        }
        __syncthreads();

        short8 ah[2], al[2];
#pragma unroll
        for (int i = 0; i < 2; ++i) {
            ah[i] = *(const short8*)&As[0][wr + i * 16 + lm][lk];
            al[i] = *(const short8*)&As[1][wr + i * 16 + lm][lk];
        }
#pragma unroll
        for (int j = 0; j < NJ; ++j) {     // load one B column-tile at a time
            short8 bh = *(const short8*)&Bs[0][wc + j * 16 + lm][lk];
            short8 bl = *(const short8*)&Bs[1][wc + j * 16 + lm][lk];
#pragma unroll
            for (int i = 0; i < 2; ++i) {
                acc[i][j] = __builtin_amdgcn_mfma_f32_16x16x32_bf16(ah[i], bh, acc[i][j], 0, 0, 0);
                acc[i][j] = __builtin_amdgcn_mfma_f32_16x16x32_bf16(ah[i], bl, acc[i][j], 0, 0, 0);
                acc[i][j] = __builtin_amdgcn_mfma_f32_16x16x32_bf16(al[i], bh, acc[i][j], 0, 0, 0);
            }
        }
        __syncthreads();
    }

#pragma unroll
    for (int i = 0; i < 2; ++i) {
#pragma unroll
        for (int r = 0; r < 4; ++r) {
            int rowi = m0 + wr + i * 16 + (lane >> 4) * 4 + r;
            if (rowi < M) {
                float dr = 1.0f / sqrtf((float)(deg[rowi] + 1));
#pragma unroll
                for (int j = 0; j < NJ; ++j) {
                    C[(size_t)rowi * N + wc + j * 16 + lm] = (_Float16)(dr * acc[i][j][r]);
                }
            }
        }
    }
}

// ---------------------------------------------------------------------------
// XCD-sliced gather over ushort slot-CSR, fp16 X table. Slice = 64 ch;
// 32 lanes per node (half2/lane) -> 2 nodes/wave, 8 nodes/block. One edge
// row-slice = 128 B contiguous. Halved slice count (vs 32-ch) halves the
// srcs/deg re-read traffic and the per-wave tail divergence.
// X rows are dinv[src]-prescaled by the GEMM epilogue.
// MODE 0: fp32 NT store to final out. MODE 1: relu + bf16 hi/lo planes
// (feeds gemm2's pure-copy staging; more accurate than fp16).
// ---------------------------------------------------------------------------
template <int C, int NSLICE, int MODE>
__global__ __launch_bounds__(256)
void gather_sliced_kernel(const _Float16* __restrict__ X, const int* __restrict__ deg,
                          const unsigned short* __restrict__ srcs,
                          const float* __restrict__ bias, float* __restrict__ outf,
                          unsigned short* __restrict__ outhi, unsigned short* __restrict__ outlo,
                          int n) {
    constexpr int SW = C / NSLICE;
    static_assert(SW == 64, "slice must be 64 channels");
    const int slice = blockIdx.x % NSLICE;
    const int ngrp  = blockIdx.x / NSLICE;
    const int wave = threadIdx.x >> 6;
    const int lane = threadIdx.x & 63;
    const int gg = lane >> 5;          // node sub-group 0..1
    const int sl = lane & 31;          // sublane: 2 channels each
    const int node = ngrp * 8 + wave * 2 + gg;
    if (node >= n) return;
    const int choff = slice * SW + sl * 2;
    const size_t beg = (size_t)node * CAP;
    const int cnt = deg[node];

    float a0 = 0.f, a1 = 0.f;
    int e = 0;
    for (; e + 4 <= cnt; e += 4) {
        ushort4v s4 = *(const ushort4v*)(srcs + beg + e);
        half2v v0 = *(const half2v*)(X + (size_t)s4.x * C + choff);
        half2v v1 = *(const half2v*)(X + (size_t)s4.y * C + choff);
        half2v v2 = *(const half2v*)(X + (size_t)s4.z * C + choff);
        half2v v3 = *(const half2v*)(X + (size_t)s4.w * C + choff);
        a0 += (float)v0.x + (float)v1.x + (float)v2.x + (float)v3.x;
        a1 += (float)v0.y + (float)v1.y + (float)v2.y + (float)v3.y;
    }
    for (; e < cnt; ++e) {
        int r = srcs[beg + e];
        half2v v = *(const half2v*)(X + (size_t)r * C + choff);
        a0 += (float)v.x; a1 += (float)v.y;
    }

    const float dc = 1.0f / sqrtf((float)(cnt + 1));
    half2v vsh = *(const half2v*)(X + (size_t)node * C + choff);  // dinv-prescaled
    float2 bb = *(const float2*)(bias + choff);

    float o0 = dc * (a0 + (float)vsh.x) + bb.x;
    float o1 = dc * (a1 + (float)vsh.y) + bb.y;

    if constexpr (MODE == 1) {
        float r0 = fmaxf(o0, 0.f), r1 = fmaxf(o1, 0.f);
        ushort2v hv, lv;
        hv.x = f2bf(r0); lv.x = f2bf(r0 - bf2f(hv.x));
        hv.y = f2bf(r1); lv.y = f2bf(r1 - bf2f(hv.y));
        *(ushort2v*)(outhi + (size_t)node * C + choff) = hv;
        *(ushort2v*)(outlo + (size_t)node * C + choff) = lv;
    } else {
        floatx2 o = {o0, o1};
        __builtin_nontemporal_store(o, (floatx2*)(outf + (size_t)node * C + choff));
    }
}

// ---------------------------------------------------------------------------
extern "C" void kernel_launch(void* const* d_in, const int* in_sizes, int n_in,
                              void* d_out, int out_size, void* d_ws, size_t ws_size,
                              hipStream_t stream) {
    const float* doc_embeds = (const float*)d_in[0];   // [20000,256]
    const int*   edge_index = (const int*)d_in[1];     // [2,320000]
    const float* W1 = (const float*)d_in[2];           // [256,256]
    const float* b1 = (const float*)d_in[3];           // [256]
    const float* W2 = (const float*)d_in[4];           // [256,128]
    const float* b2 = (const float*)d_in[5];           // [128]
    float* out = (float*)d_out;                        // [20000,128]

    const int* row = edge_index;            // sources
    const int* col = edge_index + N_EDGES;  // destinations

    // ---------------- workspace layout (256B aligned) ----------------
    char* ws = (char*)d_ws;
    auto au = [](size_t x) { return (x + 255) / 256 * 256; };

    _Float16* X1s = (_Float16*)ws;      ws += au((size_t)N_NODES * HID_CH * 2);  // 10.24 MB (gemm2 out aliases)
    unsigned short* H1hi = (unsigned short*)ws; ws += au((size_t)N_NODES * HID_CH * 2);
    unsigned short* H1lo = (unsigned short*)ws; ws += au((size_t)N_NODES * HID_CH * 2);
    unsigned short* W1thi = (unsigned short*)ws; ws += au((size_t)IN_CH * HID_CH * 2);
    unsigned short* W1tlo = (unsigned short*)ws; ws += au((size_t)IN_CH * HID_CH * 2);
    unsigned short* W2thi = (unsigned short*)ws; ws += au((size_t)HID_CH * OUT_CH * 2);
    unsigned short* W2tlo = (unsigned short*)ws; ws += au((size_t)HID_CH * OUT_CH * 2);
    int*            deg   = (int*)ws;            ws += au((size_t)N_NODES * 4);
    unsigned short* srcs  = (unsigned short*)ws; // 20000*64*2 = 2.56 MB

    // ---------------- prep ----------------
    hipMemsetAsync(deg, 0, (size_t)N_NODES * 4, stream);
    prep_kernel<<<(N_EDGES + 255) / 256, 256, 0, stream>>>(
        W1, W2, W1thi, W1tlo, W2thi, W2tlo, row, col, deg, srcs);

    // ---------------- layer 1: gemm (A read once, full N per block) ----------------
    {
        dim3 grid(1, (N_NODES + 63) / 64);   // 313 blocks, TN=256
        gemm_mfma_kernel<1, 256><<<grid, 256, 0, stream>>>(
            doc_embeds, nullptr, nullptr, W1thi, W1tlo, deg, X1s, N_NODES, HID_CH);
    }
    gather_sliced_kernel<HID_CH, 4, 1><<<((N_NODES + 7) / 8) * 4, 256, 0, stream>>>(
        X1s, deg, srcs, b1, nullptr, H1hi, H1lo, N_NODES);

    // ---------------- layer 2 ----------------
    {
        dim3 grid(1, (N_NODES + 63) / 64);   // 313 blocks, TN=128
        gemm_mfma_kernel<3, 128><<<grid, 256, 0, stream>>>(
            nullptr, H1hi, H1lo, W2thi, W2tlo, deg, X1s, N_NODES, OUT_CH);
    }
    gather_sliced_kernel<OUT_CH, 2, 0><<<((N_NODES + 7) / 8) * 2, 256, 0, stream>>>(
        X1s, deg, srcs, b2, out, nullptr, nullptr, N_NODES);
}